// Round 3
// baseline (227.705 us; speedup 1.0000x reference)
//
#include <hip/hip_runtime.h>
#include <hip/hip_fp16.h>

typedef _Float16 f16;
typedef _Float16 f16x4 __attribute__((ext_vector_type(4)));
typedef _Float16 f16x8 __attribute__((ext_vector_type(8)));
typedef float    f32x4 __attribute__((ext_vector_type(4)));

constexpr int TREES = 16;
constexpr int NNODE = 255;
constexpr int NCLS  = 100;
constexpr int NCPAD = 112;
constexpr int NB    = 8192;
constexpr int DF    = 1024;
constexpr int KTOT  = TREES * 256;   // 4096

// workspace layout (half-element offsets)
constexpr size_t XH_OFF = 0;                                    // [8192][1024] f16
constexpr size_t WH_OFF = XH_OFF + (size_t)NB * DF;             // [16][256][1024] f16
constexpr size_t SD_OFF = WH_OFF + (size_t)TREES * 256 * DF;    // [112][4096] f16
constexpr size_t BP_OFF = SD_OFF + (size_t)NCPAD * KTOT;        // [16][256] f32 padded bias
constexpr size_t PT_OFF_F = (BP_OFF + 8192) / 2;                // [16][8192][100] f32 partials

#define WAIT_VMCNT(n) asm volatile("s_waitcnt vmcnt(" #n ")" ::: "memory")
__device__ __forceinline__ void BAR() {
  asm volatile("" ::: "memory");
  __builtin_amdgcn_s_barrier();
  asm volatile("" ::: "memory");
}

__device__ __forceinline__ void gload_lds16(const f16* g, f16* l) {
  __builtin_amdgcn_global_load_lds(
      (const __attribute__((address_space(1))) void*)g,
      (__attribute__((address_space(3))) void*)l, 16, 0, 0);
}

// ---------------- prep: fp32->fp16 conversions (x and padded w) ----------------
__global__ void cvt_all_k(const float* __restrict__ x, const float* __restrict__ w,
                          f16* __restrict__ xh, f16* __restrict__ wh) {
  int bid = blockIdx.x;
  if (bid < 4096) {
    int i = bid * 256 + threadIdx.x;
    const float4* s = (const float4*)x + (size_t)i * 2;
    float4 u = s[0], v = s[1];
    f16x8 h = {(f16)u.x, (f16)u.y, (f16)u.z, (f16)u.w,
               (f16)v.x, (f16)v.y, (f16)v.z, (f16)v.w};
    *((f16x8*)xh + i) = h;
  } else {
    int i = (bid - 4096) * 256 + threadIdx.x;
    int flat = i * 8;
    int t = flat >> 18;
    int r = (flat >> 10) & 255;
    int k = flat & 1023;
    f16x8 h;
    if (r < NNODE) {
      const float4* s = (const float4*)(w + ((size_t)(t * NNODE + r) * DF + k));
      float4 u = s[0], v = s[1];
      h = (f16x8){(f16)u.x, (f16)u.y, (f16)u.z, (f16)u.w,
                  (f16)v.x, (f16)v.y, (f16)v.z, (f16)v.w};
    } else {
      h = (f16x8){(f16)0.f, (f16)0.f, (f16)0.f, (f16)0.f,
                  (f16)0.f, (f16)0.f, (f16)0.f, (f16)0.f};
    }
    *((f16x8*)wh + i) = h;
  }
}

// leaf softmax * softmax(tree_weights) transposed + padded bias
__global__ void prep_sdist_k(const float* __restrict__ ll,
                             const float* __restrict__ twin,
                             const float* __restrict__ sb,
                             f16* __restrict__ sdt,
                             float* __restrict__ bp) {
  int id = blockIdx.x * 64 + threadIdx.x;        // 0..4095 = t*256 + l
  int t = id >> 8;
  int node = id & 255;
  bp[id] = (node < NNODE) ? sb[t * NNODE + node] : 0.f;

  float wm = -1e30f;
#pragma unroll
  for (int i = 0; i < 16; ++i) wm = fmaxf(wm, twin[i]);
  float wsum = 0.f;
#pragma unroll
  for (int i = 0; i < 16; ++i) wsum += __expf(twin[i] - wm);
  float wt = __expf(twin[t] - wm) / wsum;

  const float* rowp = ll + (size_t)id * NCLS;
  float mx = -1e30f;
  for (int c = 0; c < NCLS; c += 4) {
    float4 v = *(const float4*)(rowp + c);
    mx = fmaxf(fmaxf(fmaxf(mx, v.x), v.y), fmaxf(v.z, v.w));
  }
  float s = 0.f;
  for (int c = 0; c < NCLS; c += 4) {
    float4 v = *(const float4*)(rowp + c);
    s += __expf(v.x - mx) + __expf(v.y - mx) + __expf(v.z - mx) + __expf(v.w - mx);
  }
  float inv = wt / s;
  for (int c = 0; c < NCLS; ++c)
    sdt[(size_t)c * KTOT + id] = (f16)(__expf(rowp[c] - mx) * inv);
  for (int c = NCLS; c < NCPAD; ++c)
    sdt[(size_t)c * KTOT + id] = (f16)0.f;
}

// ---------------- fused 256x256 8-wave GEMM + sigmoid + mu + leaf-GEMM ----------------
// grid 512 = 16 trees x 32 row-blocks. 512 thr (8 waves, 2M x 4N, wave tile 128x64).
// BK=64, K=1024 = 16 K-tiles, dbuf LDS, counted vmcnt, 2 barriers/K-tile.
__global__ __launch_bounds__(512, 2) void tree_gemm1(
    const f16* __restrict__ xh, const f16* __restrict__ wh,
    const float* __restrict__ biasp, const f16* __restrict__ sdt,
    float* __restrict__ ptree) {
  __shared__ f16 smem[81920];  // 160 KiB
  char* smb = (char*)smem;

  const int tid  = threadIdx.x;
  const int lane = tid & 63;
  const int wid  = tid >> 6;
  const int l15  = lane & 15;
  const int lq   = lane >> 4;
  const int wrow = (wid >> 2) * 128;
  const int wcol = (wid & 3) * 64;

  // XCD-aware decode: 2 trees per XCD
  int bid  = blockIdx.x;
  int t    = (bid & 7) | ((bid >> 8) << 3);
  int brow = (bid >> 3) & 31;

  const f16* xsrc = xh + (size_t)brow * 256 * DF;
  const f16* wsrc = wh + (size_t)t * 256 * DF;

  // stage half a K-tile (4 gload_lds: 2 A-chunks + 2 B-chunks per thread).
  // buf c: A at bytes [c*64K, c*64K+32K), B next 32K. swizzle: chunk ^= (row&7)
  auto stage_half = [&](int kt, int c, int half) {
    f16* Ab = smem + c * 32768;
    f16* Bb = Ab + 16384;
    const f16* xk = xsrc + kt * 64;
    const f16* wk = wsrc + kt * 64;
#pragma unroll
    for (int i = half * 2; i < half * 2 + 2; ++i) {
      int q = i * 512 + tid;
      int r = q >> 3;
      int ci = (q & 7) ^ (r & 7);
      gload_lds16(xk + (size_t)r * DF + ci * 8, Ab + q * 8);
    }
#pragma unroll
    for (int i = half * 2; i < half * 2 + 2; ++i) {
      int q = i * 512 + tid;
      int r = q >> 3;
      int ci = (q & 7) ^ (r & 7);
      gload_lds16(wk + (size_t)r * DF + ci * 8, Bb + q * 8);
    }
  };

  f32x4 acc[8][4];
#pragma unroll
  for (int m = 0; m < 8; ++m)
#pragma unroll
    for (int n = 0; n < 4; ++n) acc[m][n] = (f32x4){0.f, 0.f, 0.f, 0.f};

  // prologue: tile 0 fully staged into buf0
  stage_half(0, 0, 0);
  stage_half(0, 0, 1);

  for (int kt = 0; kt < 16; ++kt) {
    const int c = kt & 1;
    // issue first half of next tile's loads, then wait for THIS tile (counted)
    if (kt < 15) {
      stage_half(kt + 1, c ^ 1, 0);
      WAIT_VMCNT(4);
    } else {
      WAIT_VMCNT(0);
    }
    BAR();   // buf[c] staged for all waves

    const char* Ab = smb + c * 65536;
    const char* Bb = Ab + 32768;
#pragma unroll
    for (int s = 0; s < 2; ++s) {
      f16x8 af[8], bf[4];
#pragma unroll
      for (int m = 0; m < 8; ++m) {
        int r = wrow + m * 16 + l15;
        af[m] = *(const f16x8*)(Ab + ((r * 128 + s * 64 + lq * 16) ^ ((r & 7) << 4)));
      }
#pragma unroll
      for (int n = 0; n < 4; ++n) {
        int node = wcol + n * 16 + l15;
        bf[n] = *(const f16x8*)(Bb + ((node * 128 + s * 64 + lq * 16) ^ ((node & 7) << 4)));
      }
      if (s == 0 && kt < 15) stage_half(kt + 1, c ^ 1, 1);
      // swapped operands: lane holds row=l15 (batch row), regs = 4 consecutive node cols
#pragma unroll
      for (int m = 0; m < 8; ++m)
#pragma unroll
        for (int n = 0; n < 4; ++n)
          acc[m][n] = __builtin_amdgcn_mfma_f32_16x16x32_f16(bf[n], af[m], acc[m][n], 0, 0, 0);
    }
    BAR();   // all waves done reading buf[c] before next tile overwrites it
  }

  // ---- epilogue-1 compute (all waves): bias + sigmoid, packed to f16x4 ----
  f16x4 ph[8][4];
#pragma unroll
  for (int m = 0; m < 8; ++m) {
#pragma unroll
    for (int n = 0; n < 4; ++n) {
      int col = wcol + n * 16 + lq * 4;
      float4 b4 = *(const float4*)(biasp + t * 256 + col);
#pragma unroll
      for (int reg = 0; reg < 4; ++reg) {
        float bv = (reg == 0) ? b4.x : (reg == 1) ? b4.y : (reg == 2) ? b4.z : b4.w;
        float z = acc[m][n][reg] + bv;
        ph[m][n][reg] = (f16)__builtin_amdgcn_rcpf(1.f + __expf(-z));
      }
    }
  }

  // LDS regions for epilogue: S=[0,32K) sdt, U=[32K,96K) mu, P=[96K,160K) probs
  char* Sb = smb;
  char* Ub = smb + 32768;
  char* Pb = smb + 98304;

  auto stage_sdt = [&](int c0, int nrows) {
    int nch = nrows * 32;
    for (int q = tid; q < nch; q += 512) {
      int rr = q >> 5;
      int jj = q & 31;
      gload_lds16(sdt + (size_t)(c0 + rr) * KTOT + t * 256 + ((jj * 8) ^ ((rr & 7) << 3)),
                  smem + q * 8);
    }
  };

  for (int h = 0; h < 2; ++h) {
    // write this half's sigmoid probs: P[128][256] f16, swizzle (r&15)<<3 (b64 writes)
    if ((wid >> 2) == h) {
#pragma unroll
      for (int m = 0; m < 8; ++m) {
#pragma unroll
        for (int n = 0; n < 4; ++n) {
          int r = m * 16 + l15;
          int colb = (wcol + n * 16 + lq * 4) * 2;
          *(f16x4*)(Pb + ((r * 512 + colb) ^ ((r & 15) << 3))) = ph[m][n];
        }
      }
    }
    __syncthreads();

    // mu pass: 512 thr = 128 rows x 4 chunks of 64 leaves
    {
      int r = tid >> 2;
      int chunk = tid & 3;
      auto PR = [&](int node) -> float {
        return (float)*(const f16*)(Pb + ((r * 512 + node * 2) ^ ((r & 15) << 3)));
      };
      float p0 = PR(0);
      float p1 = PR(1 + (chunk >> 1));
      float pr = ((chunk >> 1) ? p0 : 1.f - p0) * ((chunk & 1) ? p1 : 1.f - p1);
      float p2 = PR(3 + chunk);
      float cur[64];
      {
        float mp = pr * p2;
        cur[1] = mp;
        cur[0] = pr - mp;
      }
#pragma unroll
      for (int d = 3; d <= 7; ++d) {
        int sfan = 1 << (d - 2);
        int nb = (1 << d) - 1 + (chunk << (d - 2));
#pragma unroll
        for (int i = sfan - 1; i >= 0; --i) {
          float p = PR(nb + i);
          float mv = cur[i];
          float mp = mv * p;
          cur[2 * i + 1] = mp;
          cur[2 * i] = mv - mp;
        }
      }
      // write mu -> U [128][256] f16, swizzle (r&7)<<4
#pragma unroll
      for (int g = 0; g < 8; ++g) {
        f16x8 v;
#pragma unroll
        for (int jj = 0; jj < 8; ++jj) v[jj] = (f16)cur[g * 8 + jj];
        *(f16x8*)(Ub + ((r * 512 + chunk * 128 + g * 16) ^ ((r & 7) << 4))) = v;
      }
    }
    __syncthreads();

    // leaf-GEMM: out(128x112) = mu(128x256) @ sdt_t(112x256); wave w: rows w*16..
    f32x4 acc2[7];
#pragma unroll
    for (int n = 0; n < 7; ++n) acc2[n] = (f32x4){0.f, 0.f, 0.f, 0.f};
    int arow = wid * 16 + l15;

    stage_sdt(0, 64);
    WAIT_VMCNT(0);
    __syncthreads();
#pragma unroll
    for (int n = 0; n < 4; ++n) {
#pragma unroll
      for (int s = 0; s < 8; ++s) {
        f16x8 a = *(const f16x8*)(Ub + ((arow * 512 + s * 64 + lq * 16) ^ ((arow & 7) << 4)));
        int br = n * 16 + l15;
        f16x8 b = *(const f16x8*)(Sb + ((br * 512 + s * 64 + lq * 16) ^ ((br & 7) << 4)));
        acc2[n] = __builtin_amdgcn_mfma_f32_16x16x32_f16(a, b, acc2[n], 0, 0, 0);
      }
    }
    __syncthreads();
    stage_sdt(64, 48);
    WAIT_VMCNT(0);
    __syncthreads();
#pragma unroll
    for (int n = 4; n < 7; ++n) {
#pragma unroll
      for (int s = 0; s < 8; ++s) {
        f16x8 a = *(const f16x8*)(Ub + ((arow * 512 + s * 64 + lq * 16) ^ ((arow & 7) << 4)));
        int br = (n - 4) * 16 + l15;
        f16x8 b = *(const f16x8*)(Sb + ((br * 512 + s * 64 + lq * 16) ^ ((br & 7) << 4)));
        acc2[n] = __builtin_amdgcn_mfma_f32_16x16x32_f16(a, b, acc2[n], 0, 0, 0);
      }
    }

    // store per-tree partials: ptree[t][brow*256 + h*128 + r][c]
    float* pt = ptree + ((size_t)t * NB + brow * 256 + h * 128) * NCLS;
#pragma unroll
    for (int n = 0; n < 7; ++n) {
      int col = n * 16 + l15;
      if (col < NCLS) {
#pragma unroll
        for (int reg = 0; reg < 4; ++reg) {
          int r = wid * 16 + lq * 4 + reg;
          pt[(size_t)r * NCLS + col] = acc2[n][reg];
        }
      }
    }
    if (h == 0) __syncthreads();   // protect P/U before half 1 overwrites
  }
}

// ---------------- reduce over trees ----------------
__global__ void reduce_k(const float* __restrict__ pt, float* __restrict__ out) {
  int i = blockIdx.x * 256 + threadIdx.x;
  constexpr size_t STRIDE4 = (size_t)NB * NCLS / 4;
  const float4* p = (const float4*)pt + i;
  float4 s = p[0];
#pragma unroll
  for (int t = 1; t < TREES; ++t) {
    float4 v = p[t * STRIDE4];
    s.x += v.x; s.y += v.y; s.z += v.z; s.w += v.w;
  }
  ((float4*)out)[i] = s;
}

// ---------------- launch ----------------
extern "C" void kernel_launch(void* const* d_in, const int* in_sizes, int n_in,
                              void* d_out, int out_size, void* d_ws, size_t ws_size,
                              hipStream_t stream) {
  const float* x  = (const float*)d_in[0];
  const float* sw = (const float*)d_in[1];
  const float* sb = (const float*)d_in[2];
  const float* ll = (const float*)d_in[3];
  const float* tw = (const float*)d_in[4];
  float* out = (float*)d_out;

  f16* ws  = (f16*)d_ws;
  f16* xh  = ws + XH_OFF;
  f16* wh  = ws + WH_OFF;
  f16* sdt = ws + SD_OFF;
  float* biasp = (float*)(ws + BP_OFF);
  float* ptree = (float*)d_ws + PT_OFF_F;

  cvt_all_k<<<6144, 256, 0, stream>>>(x, sw, xh, wh);
  prep_sdist_k<<<64, 64, 0, stream>>>(ll, tw, sb, sdt, biasp);
  tree_gemm1<<<512, 512, 0, stream>>>(xh, wh, biasp, sdt, ptree);
  reduce_k<<<(NB * NCLS / 4) / 256, 256, 0, stream>>>(ptree, out);
}

// Round 4
// 224.836 us; speedup vs baseline: 1.0128x; 1.0128x over previous
//
#include <hip/hip_runtime.h>
#include <hip/hip_fp16.h>

typedef _Float16 f16;
typedef _Float16 f16x4 __attribute__((ext_vector_type(4)));
typedef _Float16 f16x8 __attribute__((ext_vector_type(8)));
typedef float    f32x4 __attribute__((ext_vector_type(4)));

constexpr int TREES = 16;
constexpr int NNODE = 255;
constexpr int NCLS  = 100;
constexpr int NCPAD = 112;
constexpr int NB    = 8192;
constexpr int DF    = 1024;
constexpr int KTOT  = TREES * 256;   // 4096

// workspace layout (half-element offsets)
constexpr size_t XH_OFF = 0;                                    // [8192][1024] f16
constexpr size_t WH_OFF = XH_OFF + (size_t)NB * DF;             // [16][256][1024] f16
constexpr size_t SD_OFF = WH_OFF + (size_t)TREES * 256 * DF;    // [112][4096] f16
constexpr size_t BP_OFF = SD_OFF + (size_t)NCPAD * KTOT;        // [16][256] f32 padded bias
constexpr size_t PT_OFF_F = (BP_OFF + 8192) / 2;                // [16][8192][100] f32 partials

#define WAIT_VMCNT(n) asm volatile("s_waitcnt vmcnt(" #n ")" ::: "memory")
__device__ __forceinline__ void BAR() {
  asm volatile("" ::: "memory");
  __builtin_amdgcn_s_barrier();
  asm volatile("" ::: "memory");
}

__device__ __forceinline__ void gload_lds16(const f16* g, f16* l) {
  __builtin_amdgcn_global_load_lds(
      (const __attribute__((address_space(1))) void*)g,
      (__attribute__((address_space(3))) void*)l, 16, 0, 0);
}

// ---------------- prep: fp32->fp16 conversions (x and padded w) ----------------
__global__ void cvt_all_k(const float* __restrict__ x, const float* __restrict__ w,
                          f16* __restrict__ xh, f16* __restrict__ wh) {
  int bid = blockIdx.x;
  if (bid < 4096) {
    int i = bid * 256 + threadIdx.x;
    const float4* s = (const float4*)x + (size_t)i * 2;
    float4 u = s[0], v = s[1];
    f16x8 h = {(f16)u.x, (f16)u.y, (f16)u.z, (f16)u.w,
               (f16)v.x, (f16)v.y, (f16)v.z, (f16)v.w};
    *((f16x8*)xh + i) = h;
  } else {
    int i = (bid - 4096) * 256 + threadIdx.x;
    int flat = i * 8;
    int t = flat >> 18;
    int r = (flat >> 10) & 255;
    int k = flat & 1023;
    f16x8 h;
    if (r < NNODE) {
      const float4* s = (const float4*)(w + ((size_t)(t * NNODE + r) * DF + k));
      float4 u = s[0], v = s[1];
      h = (f16x8){(f16)u.x, (f16)u.y, (f16)u.z, (f16)u.w,
                  (f16)v.x, (f16)v.y, (f16)v.z, (f16)v.w};
    } else {
      h = (f16x8){(f16)0.f, (f16)0.f, (f16)0.f, (f16)0.f,
                  (f16)0.f, (f16)0.f, (f16)0.f, (f16)0.f};
    }
    *((f16x8*)wh + i) = h;
  }
}

// leaf softmax * softmax(tree_weights), transposed, wave-parallel: one wave per row
__global__ void prep_sdist_k(const float* __restrict__ ll,
                             const float* __restrict__ twin,
                             const float* __restrict__ sb,
                             f16* __restrict__ sdt,
                             float* __restrict__ bp) {
  int wv   = threadIdx.x >> 6;
  int lane = threadIdx.x & 63;
  int id   = blockIdx.x * 4 + wv;        // 0..4095 = t*256 + node
  int t    = id >> 8;
  int node = id & 255;

  float wm = -1e30f;
#pragma unroll
  for (int i = 0; i < 16; ++i) wm = fmaxf(wm, twin[i]);
  float wsum = 0.f;
#pragma unroll
  for (int i = 0; i < 16; ++i) wsum += __expf(twin[i] - wm);
  float wt = __expf(twin[t] - wm) / wsum;

  const float* rowp = ll + (size_t)id * NCLS;
  float v1 = rowp[lane];                       // lane < 64 < 100: always valid
  bool has2 = (lane + 64) < NCLS;              // lane < 36
  float v2 = has2 ? rowp[lane + 64] : -1e30f;
  float mx = fmaxf(v1, v2);
#pragma unroll
  for (int m = 32; m; m >>= 1) mx = fmaxf(mx, __shfl_xor(mx, m, 64));
  float e1 = __expf(v1 - mx);
  float e2 = has2 ? __expf(v2 - mx) : 0.f;
  float ss = e1 + e2;
#pragma unroll
  for (int m = 32; m; m >>= 1) ss += __shfl_xor(ss, m, 64);
  float inv = wt / ss;

  sdt[(size_t)lane * KTOT + id] = (f16)(e1 * inv);
  if (lane + 64 < NCPAD)
    sdt[(size_t)(lane + 64) * KTOT + id] = has2 ? (f16)(e2 * inv) : (f16)0.f;
  if (lane == 0) bp[id] = (node < NNODE) ? sb[(size_t)t * NNODE + node] : 0.f;
}

// ---------------- fused 256x256 8-wave GEMM + sigmoid + mu + leaf-GEMM ----------------
// grid 512. 512 thr (8 waves, 2M x 4N, wave tile 128x64). BK=64, K=1024 = 16 K-tiles,
// dbuf LDS, counted vmcnt, 2 barriers/K-tile.
// XCD rectangle partition: xcd gets 8 trees x 8 row-blocks (L2 fill 4.2+4.2 MB).
__global__ __launch_bounds__(512, 2) void tree_gemm1(
    const f16* __restrict__ xh, const f16* __restrict__ wh,
    const float* __restrict__ biasp, const f16* __restrict__ sdt,
    float* __restrict__ ptree) {
  __shared__ f16 smem[81920];  // 160 KiB
  char* smb = (char*)smem;

  const int tid  = threadIdx.x;
  const int lane = tid & 63;
  const int wid  = tid >> 6;
  const int l15  = lane & 15;
  const int lq   = lane >> 4;
  const int wrow = (wid >> 2) * 128;
  const int wcol = (wid & 3) * 64;

  // XCD rectangle decode: blockIdx round-robins XCDs (bid%8).
  int bid  = blockIdx.x;
  int xcd  = bid & 7;
  int idx  = bid >> 3;                  // 0..63 within this XCD
  int t    = (xcd & 1) * 8 + (idx & 7);
  int brow = (xcd >> 1) * 8 + (idx >> 3);

  const f16* xsrc = xh + (size_t)brow * 256 * DF;
  const f16* wsrc = wh + (size_t)t * 256 * DF;

  // stage half a K-tile (4 gload_lds: 2 A-chunks + 2 B-chunks per thread).
  auto stage_half = [&](int kt, int c, int half) {
    f16* Ab = smem + c * 32768;
    f16* Bb = Ab + 16384;
    const f16* xk = xsrc + kt * 64;
    const f16* wk = wsrc + kt * 64;
#pragma unroll
    for (int i = half * 2; i < half * 2 + 2; ++i) {
      int q = i * 512 + tid;
      int r = q >> 3;
      int ci = (q & 7) ^ (r & 7);
      gload_lds16(xk + (size_t)r * DF + ci * 8, Ab + q * 8);
    }
#pragma unroll
    for (int i = half * 2; i < half * 2 + 2; ++i) {
      int q = i * 512 + tid;
      int r = q >> 3;
      int ci = (q & 7) ^ (r & 7);
      gload_lds16(wk + (size_t)r * DF + ci * 8, Bb + q * 8);
    }
  };

  f32x4 acc[8][4];
#pragma unroll
  for (int m = 0; m < 8; ++m)
#pragma unroll
    for (int n = 0; n < 4; ++n) acc[m][n] = (f32x4){0.f, 0.f, 0.f, 0.f};

  stage_half(0, 0, 0);
  stage_half(0, 0, 1);

  for (int kt = 0; kt < 16; ++kt) {
    const int c = kt & 1;
    if (kt < 15) {
      stage_half(kt + 1, c ^ 1, 0);
      WAIT_VMCNT(4);
    } else {
      WAIT_VMCNT(0);
    }
    BAR();

    const char* Ab = smb + c * 65536;
    const char* Bb = Ab + 32768;
#pragma unroll
    for (int s = 0; s < 2; ++s) {
      f16x8 af[8], bf[4];
#pragma unroll
      for (int m = 0; m < 8; ++m) {
        int r = wrow + m * 16 + l15;
        af[m] = *(const f16x8*)(Ab + ((r * 128 + s * 64 + lq * 16) ^ ((r & 7) << 4)));
      }
#pragma unroll
      for (int n = 0; n < 4; ++n) {
        int node = wcol + n * 16 + l15;
        bf[n] = *(const f16x8*)(Bb + ((node * 128 + s * 64 + lq * 16) ^ ((node & 7) << 4)));
      }
      if (s == 0 && kt < 15) stage_half(kt + 1, c ^ 1, 1);
#pragma unroll
      for (int m = 0; m < 8; ++m)
#pragma unroll
        for (int n = 0; n < 4; ++n)
          acc[m][n] = __builtin_amdgcn_mfma_f32_16x16x32_f16(bf[n], af[m], acc[m][n], 0, 0, 0);
    }
    BAR();
  }

  // ---- epilogue-1: bias + sigmoid, packed to f16x4 ----
  f16x4 ph[8][4];
#pragma unroll
  for (int m = 0; m < 8; ++m) {
#pragma unroll
    for (int n = 0; n < 4; ++n) {
      int col = wcol + n * 16 + lq * 4;
      float4 b4 = *(const float4*)(biasp + t * 256 + col);
#pragma unroll
      for (int reg = 0; reg < 4; ++reg) {
        float bv = (reg == 0) ? b4.x : (reg == 1) ? b4.y : (reg == 2) ? b4.z : b4.w;
        float z = acc[m][n][reg] + bv;
        ph[m][n][reg] = (f16)__builtin_amdgcn_rcpf(1.f + __expf(-z));
      }
    }
  }

  char* Sb = smb;
  char* Ub = smb + 32768;
  char* Pb = smb + 98304;

  auto stage_sdt = [&](int c0, int nrows) {
    int nch = nrows * 32;
    for (int q = tid; q < nch; q += 512) {
      int rr = q >> 5;
      int jj = q & 31;
      gload_lds16(sdt + (size_t)(c0 + rr) * KTOT + t * 256 + ((jj * 8) ^ ((rr & 7) << 3)),
                  smem + q * 8);
    }
  };

  for (int h = 0; h < 2; ++h) {
    if ((wid >> 2) == h) {
#pragma unroll
      for (int m = 0; m < 8; ++m) {
#pragma unroll
        for (int n = 0; n < 4; ++n) {
          int r = m * 16 + l15;
          int colb = (wcol + n * 16 + lq * 4) * 2;
          *(f16x4*)(Pb + ((r * 512 + colb) ^ ((r & 15) << 3))) = ph[m][n];
        }
      }
    }
    __syncthreads();

    // mu pass: 512 thr = 128 rows x 4 chunks of 64 leaves
    {
      int r = tid >> 2;
      int chunk = tid & 3;
      auto PR = [&](int node) -> float {
        return (float)*(const f16*)(Pb + ((r * 512 + node * 2) ^ ((r & 15) << 3)));
      };
      float p0 = PR(0);
      float p1 = PR(1 + (chunk >> 1));
      float pr = ((chunk >> 1) ? p0 : 1.f - p0) * ((chunk & 1) ? p1 : 1.f - p1);
      float p2 = PR(3 + chunk);
      float cur[64];
      {
        float mp = pr * p2;
        cur[1] = mp;
        cur[0] = pr - mp;
      }
#pragma unroll
      for (int d = 3; d <= 7; ++d) {
        int sfan = 1 << (d - 2);
        int nb = (1 << d) - 1 + (chunk << (d - 2));
#pragma unroll
        for (int i = sfan - 1; i >= 0; --i) {
          float p = PR(nb + i);
          float mv = cur[i];
          float mp = mv * p;
          cur[2 * i + 1] = mp;
          cur[2 * i] = mv - mp;
        }
      }
#pragma unroll
      for (int g = 0; g < 8; ++g) {
        f16x8 v;
#pragma unroll
        for (int jj = 0; jj < 8; ++jj) v[jj] = (f16)cur[g * 8 + jj];
        *(f16x8*)(Ub + ((r * 512 + chunk * 128 + g * 16) ^ ((r & 7) << 4))) = v;
      }
    }
    __syncthreads();

    // leaf-GEMM: out(128x112) = mu(128x256) @ sdt_t(112x256)
    f32x4 acc2[7];
#pragma unroll
    for (int n = 0; n < 7; ++n) acc2[n] = (f32x4){0.f, 0.f, 0.f, 0.f};
    int arow = wid * 16 + l15;

    stage_sdt(0, 64);
    WAIT_VMCNT(0);
    __syncthreads();
#pragma unroll
    for (int n = 0; n < 4; ++n) {
#pragma unroll
      for (int s = 0; s < 8; ++s) {
        f16x8 a = *(const f16x8*)(Ub + ((arow * 512 + s * 64 + lq * 16) ^ ((arow & 7) << 4)));
        int br = n * 16 + l15;
        f16x8 b = *(const f16x8*)(Sb + ((br * 512 + s * 64 + lq * 16) ^ ((br & 7) << 4)));
        acc2[n] = __builtin_amdgcn_mfma_f32_16x16x32_f16(a, b, acc2[n], 0, 0, 0);
      }
    }
    __syncthreads();
    stage_sdt(64, 48);
    WAIT_VMCNT(0);
    __syncthreads();
#pragma unroll
    for (int n = 4; n < 7; ++n) {
#pragma unroll
      for (int s = 0; s < 8; ++s) {
        f16x8 a = *(const f16x8*)(Ub + ((arow * 512 + s * 64 + lq * 16) ^ ((arow & 7) << 4)));
        int br = (n - 4) * 16 + l15;
        f16x8 b = *(const f16x8*)(Sb + ((br * 512 + s * 64 + lq * 16) ^ ((br & 7) << 4)));
        acc2[n] = __builtin_amdgcn_mfma_f32_16x16x32_f16(a, b, acc2[n], 0, 0, 0);
      }
    }

    float* pt = ptree + ((size_t)t * NB + brow * 256 + h * 128) * NCLS;
#pragma unroll
    for (int n = 0; n < 7; ++n) {
      int col = n * 16 + l15;
      if (col < NCLS) {
#pragma unroll
        for (int reg = 0; reg < 4; ++reg) {
          int r = wid * 16 + lq * 4 + reg;
          pt[(size_t)r * NCLS + col] = acc2[n][reg];
        }
      }
    }
    if (h == 0) __syncthreads();
  }
}

// ---------------- reduce over trees ----------------
__global__ void reduce_k(const float* __restrict__ pt, float* __restrict__ out) {
  int i = blockIdx.x * 256 + threadIdx.x;
  constexpr size_t STRIDE4 = (size_t)NB * NCLS / 4;
  const float4* p = (const float4*)pt + i;
  float4 s = p[0];
#pragma unroll
  for (int t = 1; t < TREES; ++t) {
    float4 v = p[t * STRIDE4];
    s.x += v.x; s.y += v.y; s.z += v.z; s.w += v.w;
  }
  ((float4*)out)[i] = s;
}

// ---------------- launch ----------------
extern "C" void kernel_launch(void* const* d_in, const int* in_sizes, int n_in,
                              void* d_out, int out_size, void* d_ws, size_t ws_size,
                              hipStream_t stream) {
  const float* x  = (const float*)d_in[0];
  const float* sw = (const float*)d_in[1];
  const float* sb = (const float*)d_in[2];
  const float* ll = (const float*)d_in[3];
  const float* tw = (const float*)d_in[4];
  float* out = (float*)d_out;

  f16* ws  = (f16*)d_ws;
  f16* xh  = ws + XH_OFF;
  f16* wh  = ws + WH_OFF;
  f16* sdt = ws + SD_OFF;
  float* biasp = (float*)(ws + BP_OFF);
  float* ptree = (float*)d_ws + PT_OFF_F;

  cvt_all_k<<<6144, 256, 0, stream>>>(x, sw, xh, wh);
  prep_sdist_k<<<1024, 256, 0, stream>>>(ll, tw, sb, sdt, biasp);
  tree_gemm1<<<512, 512, 0, stream>>>(xh, wh, biasp, sdt, ptree);
  reduce_k<<<(NB * NCLS / 4) / 256, 256, 0, stream>>>(ptree, out);
}

// Round 6
// 205.853 us; speedup vs baseline: 1.1062x; 1.0922x over previous
//
#include <hip/hip_runtime.h>
#include <hip/hip_fp16.h>

typedef _Float16 f16;
typedef _Float16 f16x4 __attribute__((ext_vector_type(4)));
typedef _Float16 f16x8 __attribute__((ext_vector_type(8)));
typedef float    f32x4 __attribute__((ext_vector_type(4)));

constexpr int TREES = 16;
constexpr int NNODE = 255;
constexpr int NCLS  = 100;
constexpr int NCPAD = 112;
constexpr int NB    = 8192;
constexpr int DF    = 1024;
constexpr int KTOT  = TREES * 256;   // 4096

// workspace layout (half-element offsets)
constexpr size_t XH_OFF = 0;                                    // [8192][1024] f16
constexpr size_t WH_OFF = XH_OFF + (size_t)NB * DF;             // [16][256][1024] f16
constexpr size_t SD_OFF = WH_OFF + (size_t)TREES * 256 * DF;    // [112][4096] f16
constexpr size_t BP_OFF = SD_OFF + (size_t)NCPAD * KTOT;        // [16][256] f32 padded bias
constexpr size_t PT_OFF_F = (BP_OFF + 8192) / 2;                // [16][8192][100] f32 partials

#define WAIT_VMCNT(n) asm volatile("s_waitcnt vmcnt(" #n ")" ::: "memory")
#define WAIT_LGKM0()  asm volatile("s_waitcnt lgkmcnt(0)" ::: "memory")
__device__ __forceinline__ void BAR() {
  asm volatile("" ::: "memory");
  __builtin_amdgcn_s_barrier();
  asm volatile("" ::: "memory");
}

__device__ __forceinline__ void gload_lds16(const f16* g, f16* l) {
  __builtin_amdgcn_global_load_lds(
      (const __attribute__((address_space(1))) void*)g,
      (__attribute__((address_space(3))) void*)l, 16, 0, 0);
}

// ---------------- merged prep: x-cvt, w-cvt, leaf-softmax, bias-pad ----------------
__global__ void prep_all_k(const float* __restrict__ x, const float* __restrict__ w,
                           const float* __restrict__ ll, const float* __restrict__ twin,
                           const float* __restrict__ sb,
                           f16* __restrict__ xh, f16* __restrict__ wh,
                           f16* __restrict__ sdt, float* __restrict__ bp) {
  int bid = blockIdx.x;
  if (bid < 4096) {
    int i = bid * 256 + threadIdx.x;
    const float4* s = (const float4*)x + (size_t)i * 2;
    float4 u = s[0], v = s[1];
    f16x8 h = {(f16)u.x, (f16)u.y, (f16)u.z, (f16)u.w,
               (f16)v.x, (f16)v.y, (f16)v.z, (f16)v.w};
    *((f16x8*)xh + i) = h;
  } else if (bid < 6144) {
    int i = (bid - 4096) * 256 + threadIdx.x;
    int flat = i * 8;
    int t = flat >> 18;
    int r = (flat >> 10) & 255;
    int k = flat & 1023;
    f16x8 h;
    if (r < NNODE) {
      const float4* s = (const float4*)(w + ((size_t)(t * NNODE + r) * DF + k));
      float4 u = s[0], v = s[1];
      h = (f16x8){(f16)u.x, (f16)u.y, (f16)u.z, (f16)u.w,
                  (f16)v.x, (f16)v.y, (f16)v.z, (f16)v.w};
    } else {
      h = (f16x8){(f16)0.f, (f16)0.f, (f16)0.f, (f16)0.f,
                  (f16)0.f, (f16)0.f, (f16)0.f, (f16)0.f};
    }
    *((f16x8*)wh + i) = h;
  } else {
    int wv   = threadIdx.x >> 6;
    int lane = threadIdx.x & 63;
    int id   = (bid - 6144) * 4 + wv;    // 0..4095 = t*256 + node
    int t    = id >> 8;
    int node = id & 255;

    float wm = -1e30f;
#pragma unroll
    for (int i = 0; i < 16; ++i) wm = fmaxf(wm, twin[i]);
    float wsum = 0.f;
#pragma unroll
    for (int i = 0; i < 16; ++i) wsum += __expf(twin[i] - wm);
    float wt = __expf(twin[t] - wm) / wsum;

    const float* rowp = ll + (size_t)id * NCLS;
    float v1 = rowp[lane];
    bool has2 = (lane + 64) < NCLS;
    float v2 = has2 ? rowp[lane + 64] : -1e30f;
    float mx = fmaxf(v1, v2);
#pragma unroll
    for (int m = 32; m; m >>= 1) mx = fmaxf(mx, __shfl_xor(mx, m, 64));
    float e1 = __expf(v1 - mx);
    float e2 = has2 ? __expf(v2 - mx) : 0.f;
    float ss = e1 + e2;
#pragma unroll
    for (int m = 32; m; m >>= 1) ss += __shfl_xor(ss, m, 64);
    float inv = wt / ss;

    sdt[(size_t)lane * KTOT + id] = (f16)(e1 * inv);
    if (lane + 64 < NCPAD)
      sdt[(size_t)(lane + 64) * KTOT + id] = has2 ? (f16)(e2 * inv) : (f16)0.f;
    if (lane == 0) bp[id] = (node < NNODE) ? sb[(size_t)t * NNODE + node] : 0.f;
  }
}

// ---------------- fused 256x256 8-wave GEMM + sigmoid + mu + leaf-GEMM ----------------
// Fine-phase main loop: BK=32, 32 K-tiles, tri-buffered LDS (3 x 32KB),
// 2 phases/tile {ds_read quadrant | issue 2 gload_lds of kt+2 | BAR | lgkm0 |
// setprio(1) 16 MFMA setprio(0)}, counted vmcnt(4) at tile boundary.
__global__ __launch_bounds__(512, 2) void tree_gemm1(
    const f16* __restrict__ xh, const f16* __restrict__ wh,
    const float* __restrict__ biasp, const f16* __restrict__ sdt,
    float* __restrict__ ptree) {
  __shared__ f16 smem[81920];  // 160 KiB
  char* smb = (char*)smem;

  const int tid  = threadIdx.x;
  const int lane = tid & 63;
  const int wid  = tid >> 6;
  const int l15  = lane & 15;
  const int lq   = lane >> 4;
  const int wrow = (wid >> 2) * 128;
  const int wcol = (wid & 3) * 64;

  // XCD rectangle decode: each XCD gets 8 trees x 8 row-blocks
  int bid  = blockIdx.x;
  int xcd  = bid & 7;
  int idx  = bid >> 3;
  int t    = (xcd & 1) * 8 + (idx & 7);
  int brow = (xcd >> 1) * 8 + (idx >> 3);

  const f16* xsrc = xh + (size_t)brow * 256 * DF;
  const f16* wsrc = wh + (size_t)t * 256 * DF;

  // tribuf: buf b at bytes [b*32768, b*32768+32K): A 16K then B 16K. BK=32.
  // LDS elem (row,kk): byte = (row*64 + kk*2) ^ ((row&3)<<4)
  // pair 0 = A (2 chunks), pair 1 = B (2 chunks); chunk = 8KB (1 gload/thread)
  auto stage2 = [&](int kt, int b, int pair) {
    f16* base = smem + b * 16384 + pair * 8192;   // halves
    const f16* src = (pair == 0 ? xsrc : wsrc) + kt * 32;
#pragma unroll
    for (int ch = 0; ch < 2; ++ch) {
      int u = ch * 512 + tid;          // 16B units, 0..1023
      int r = u >> 2;
      int ci = (u & 3) ^ (r & 3);
      gload_lds16(src + (size_t)r * DF + ci * 8, base + u * 8);
    }
  };

  f32x4 acc[8][4];
#pragma unroll
  for (int m = 0; m < 8; ++m)
#pragma unroll
    for (int n = 0; n < 4; ++n) acc[m][n] = (f32x4){0.f, 0.f, 0.f, 0.f};

  // prologue: tiles 0,1 staged
  stage2(0, 0, 0); stage2(0, 0, 1);
  stage2(1, 1, 0); stage2(1, 1, 1);
  WAIT_VMCNT(4);
  BAR();

  for (int kt = 0; kt < 32; ++kt) {
    const char* Ab = smb + (kt % 3) * 32768;
    const char* Bb = Ab + 16384;
    const int nb3 = (kt + 2) % 3;
    f16x8 af[4], bf[4], ag[4];

    // ---- phase A: quadrant m0-3 ----
#pragma unroll
    for (int m = 0; m < 4; ++m) {
      int r = wrow + m * 16 + l15;
      af[m] = *(const f16x8*)(Ab + ((r * 64 + lq * 16) ^ ((r & 3) << 4)));
    }
#pragma unroll
    for (int n = 0; n < 4; ++n) {
      int r = wcol + n * 16 + l15;
      bf[n] = *(const f16x8*)(Bb + ((r * 64 + lq * 16) ^ ((r & 3) << 4)));
    }
    if (kt < 30) stage2(kt + 2, nb3, 0);
    BAR();
    WAIT_LGKM0();
    __builtin_amdgcn_sched_barrier(0);
    __builtin_amdgcn_s_setprio(1);
#pragma unroll
    for (int m = 0; m < 4; ++m)
#pragma unroll
      for (int n = 0; n < 4; ++n)
        acc[m][n] = __builtin_amdgcn_mfma_f32_16x16x32_f16(bf[n], af[m], acc[m][n], 0, 0, 0);
    __builtin_amdgcn_s_setprio(0);
    __builtin_amdgcn_sched_barrier(0);

    // ---- phase B: quadrant m4-7 ----
#pragma unroll
    for (int m = 0; m < 4; ++m) {
      int r = wrow + 64 + m * 16 + l15;
      ag[m] = *(const f16x8*)(Ab + ((r * 64 + lq * 16) ^ ((r & 3) << 4)));
    }
    if (kt < 30) stage2(kt + 2, nb3, 1);
    BAR();
    WAIT_LGKM0();
    __builtin_amdgcn_sched_barrier(0);
    __builtin_amdgcn_s_setprio(1);
#pragma unroll
    for (int m = 0; m < 4; ++m)
#pragma unroll
      for (int n = 0; n < 4; ++n)
        acc[m + 4][n] = __builtin_amdgcn_mfma_f32_16x16x32_f16(bf[n], ag[m], acc[m + 4][n], 0, 0, 0);
    __builtin_amdgcn_s_setprio(0);
    __builtin_amdgcn_sched_barrier(0);

    // ---- tile boundary: counted wait for tile kt+1 (kt+2 stays in flight) ----
    if (kt < 30)       { WAIT_VMCNT(4); BAR(); }
    else if (kt == 30) { WAIT_VMCNT(0); BAR(); }
  }

  // epilogue LDS regions: S=[0,32K) sdt, U=[32K,96K) mu, P=[96K,160K) probs
  char* Sb = smb;
  char* Ub = smb + 32768;
  char* Pb = smb + 98304;

  auto stage_sdt = [&](int c0, int nrows) {
    int nch = nrows * 32;
    for (int q = tid; q < nch; q += 512) {
      int rr = q >> 5;
      int jj = q & 31;
      gload_lds16(sdt + (size_t)(c0 + rr) * KTOT + t * 256 + ((jj * 8) ^ ((rr & 7) << 3)),
                  smem + q * 8);
    }
  };
  // pre-issue S rows 0..63 — S region (tribuf bufs 0-1 low part) is dead now;
  // overlaps sigmoid + P-write + mu of half 0.
  stage_sdt(0, 64);

  // ---- sigmoid + bias, packed f16x4 (regs = 4 consecutive nodes per row) ----
  f16x4 ph[8][4];
#pragma unroll
  for (int m = 0; m < 8; ++m) {
#pragma unroll
    for (int n = 0; n < 4; ++n) {
      int col = wcol + n * 16 + lq * 4;
      float4 b4 = *(const float4*)(biasp + t * 256 + col);
#pragma unroll
      for (int reg = 0; reg < 4; ++reg) {
        float bv = (reg == 0) ? b4.x : (reg == 1) ? b4.y : (reg == 2) ? b4.z : b4.w;
        float z = acc[m][n][reg] + bv;
        ph[m][n][reg] = (f16)__builtin_amdgcn_rcpf(1.f + __expf(-z));
      }
    }
  }

  for (int h = 0; h < 2; ++h) {
    // P[128][256] f16, 16B-granularity swizzle: byte = (r*512 + node*2) ^ ((r&7)<<4)
    if ((wid >> 2) == h) {
#pragma unroll
      for (int m = 0; m < 8; ++m) {
#pragma unroll
        for (int n = 0; n < 4; ++n) {
          int r = m * 16 + l15;
          int nodeb = (wcol + n * 16 + lq * 4) * 2;
          *(f16x4*)(Pb + ((r * 512 + nodeb) ^ ((r & 7) << 4))) = ph[m][n];
        }
      }
    }
    __syncthreads();

    // ---- mu pass: 512 thr = 128 rows x 4 chunks; vectorized P reads ----
    {
      int r = tid >> 2;
      int c = tid & 3;
      auto PRs = [&](int node) -> float {
        return (float)*(const f16*)(Pb + ((r * 512 + node * 2) ^ ((r & 7) << 4)));
      };
      auto V8 = [&](int node) -> f16x8 {   // node must be multiple of 8
        return *(const f16x8*)(Pb + ((r * 512 + node * 2) ^ ((r & 7) << 4)));
      };
      float p0 = PRs(0);
      float p1 = PRs(1 + (c >> 1));
      float pr = ((c >> 1) ? p0 : 1.f - p0) * ((c & 1) ? p1 : 1.f - p1);
      float p2 = PRs(3 + c);
      float cur[64];
      {
        float mp = pr * p2;
        cur[1] = mp; cur[0] = pr - mp;
      }
      { // d=3: nodes 7+2c, 8+2c
        float q0 = PRs(7 + 2 * c), q1 = PRs(8 + 2 * c);
        float m1 = cur[1], mp1 = m1 * q1;
        cur[3] = mp1; cur[2] = m1 - mp1;
        float m0 = cur[0], mp0 = m0 * q0;
        cur[1] = mp0; cur[0] = m0 - mp0;
      }
      { // d=4: nodes 15+4c .. 18+4c
        float q[4];
        q[0] = PRs(15 + 4 * c);
        f16x4 v = *(const f16x4*)(Pb + ((r * 512 + (16 + 4 * c) * 2) ^ ((r & 7) << 4)));
        q[1] = (float)v[0]; q[2] = (float)v[1]; q[3] = (float)v[2];
#pragma unroll
        for (int i = 3; i >= 0; --i) {
          float mv = cur[i], mp = mv * q[i];
          cur[2 * i + 1] = mp; cur[2 * i] = mv - mp;
        }
      }
      { // d=5: nodes 31+8c .. 38+8c
        float q[8];
        q[0] = PRs(31 + 8 * c);
        f16x8 v = V8(32 + 8 * c);
#pragma unroll
        for (int j = 0; j < 7; ++j) q[j + 1] = (float)v[j];
#pragma unroll
        for (int i = 7; i >= 0; --i) {
          float mv = cur[i], mp = mv * q[i];
          cur[2 * i + 1] = mp; cur[2 * i] = mv - mp;
        }
      }
      { // d=6: nodes 63+16c .. 78+16c
        float q[16];
        q[0] = PRs(63 + 16 * c);
        f16x8 v0 = V8(64 + 16 * c), v1 = V8(72 + 16 * c);
#pragma unroll
        for (int j = 0; j < 8; ++j) q[j + 1] = (float)v0[j];
#pragma unroll
        for (int j = 0; j < 7; ++j) q[j + 9] = (float)v1[j];
#pragma unroll
        for (int i = 15; i >= 0; --i) {
          float mv = cur[i], mp = mv * q[i];
          cur[2 * i + 1] = mp; cur[2 * i] = mv - mp;
        }
      }
      { // d=7: nodes 127+32c .. 158+32c
        float q[32];
        q[0] = PRs(127 + 32 * c);
        f16x8 v0 = V8(128 + 32 * c), v1 = V8(136 + 32 * c);
        f16x8 v2 = V8(144 + 32 * c), v3 = V8(152 + 32 * c);
#pragma unroll
        for (int j = 0; j < 8; ++j) q[j + 1]  = (float)v0[j];
#pragma unroll
        for (int j = 0; j < 8; ++j) q[j + 9]  = (float)v1[j];
#pragma unroll
        for (int j = 0; j < 8; ++j) q[j + 17] = (float)v2[j];
#pragma unroll
        for (int j = 0; j < 7; ++j) q[j + 25] = (float)v3[j];
#pragma unroll
        for (int i = 31; i >= 0; --i) {
          float mv = cur[i], mp = mv * q[i];
          cur[2 * i + 1] = mp; cur[2 * i] = mv - mp;
        }
      }
      // write mu -> U [128][256] f16, swizzle (r&7)<<4
#pragma unroll
      for (int g = 0; g < 8; ++g) {
        f16x8 v;
#pragma unroll
        for (int jj = 0; jj < 8; ++jj) v[jj] = (f16)cur[g * 8 + jj];
        *(f16x8*)(Ub + ((r * 512 + c * 128 + g * 16) ^ ((r & 7) << 4))) = v;
      }
    }
    WAIT_VMCNT(0);      // S chunk arrived (own wave's loads)
    __syncthreads();    // all waves: S landed + U visible

    // ---- leaf-GEMM: out(128x112) = mu(128x256) @ sdt_t(112x256) ----
    f32x4 acc2[7];
#pragma unroll
    for (int n = 0; n < 7; ++n) acc2[n] = (f32x4){0.f, 0.f, 0.f, 0.f};
    int arow = wid * 16 + l15;

#pragma unroll
    for (int n = 0; n < 4; ++n) {
#pragma unroll
      for (int s = 0; s < 8; ++s) {
        f16x8 a = *(const f16x8*)(Ub + ((arow * 512 + s * 64 + lq * 16) ^ ((arow & 7) << 4)));
        int br = n * 16 + l15;
        f16x8 b = *(const f16x8*)(Sb + ((br * 512 + s * 64 + lq * 16) ^ ((br & 7) << 4)));
        acc2[n] = __builtin_amdgcn_mfma_f32_16x16x32_f16(a, b, acc2[n], 0, 0, 0);
      }
    }
    __syncthreads();          // S rows 0..63 reads done
    stage_sdt(64, 48);        // S rows 64..111
    WAIT_VMCNT(0);
    __syncthreads();
#pragma unroll
    for (int n = 4; n < 7; ++n) {
#pragma unroll
      for (int s = 0; s < 8; ++s) {
        f16x8 a = *(const f16x8*)(Ub + ((arow * 512 + s * 64 + lq * 16) ^ ((arow & 7) << 4)));
        int br = (n - 4) * 16 + l15;
        f16x8 b = *(const f16x8*)(Sb + ((br * 512 + s * 64 + lq * 16) ^ ((br & 7) << 4)));
        acc2[n] = __builtin_amdgcn_mfma_f32_16x16x32_f16(a, b, acc2[n], 0, 0, 0);
      }
    }

    float* pt = ptree + ((size_t)t * NB + brow * 256 + h * 128) * NCLS;
#pragma unroll
    for (int n = 0; n < 7; ++n) {
      int col = n * 16 + l15;
      if (col < NCLS) {
#pragma unroll
        for (int reg = 0; reg < 4; ++reg) {
          int r = wid * 16 + lq * 4 + reg;
          pt[(size_t)r * NCLS + col] = acc2[n][reg];
        }
      }
    }
    if (h == 0) {
      __syncthreads();        // S reads + P reads of half 0 complete everywhere
      stage_sdt(0, 64);       // re-issue S rows 0..63; overlaps half-1 P-write + mu
    }
  }
}

// ---------------- reduce over trees ----------------
__global__ void reduce_k(const float* __restrict__ pt, float* __restrict__ out) {
  int i = blockIdx.x * 256 + threadIdx.x;
  constexpr size_t STRIDE4 = (size_t)NB * NCLS / 4;
  const float4* p = (const float4*)pt + i;
  float4 s = p[0];
#pragma unroll
  for (int t = 1; t < TREES; ++t) {
    float4 v = p[t * STRIDE4];
    s.x += v.x; s.y += v.y; s.z += v.z; s.w += v.w;
  }
  ((float4*)out)[i] = s;
}

// ---------------- launch ----------------
extern "C" void kernel_launch(void* const* d_in, const int* in_sizes, int n_in,
                              void* d_out, int out_size, void* d_ws, size_t ws_size,
                              hipStream_t stream) {
  const float* x  = (const float*)d_in[0];
  const float* sw = (const float*)d_in[1];
  const float* sb = (const float*)d_in[2];
  const float* ll = (const float*)d_in[3];
  const float* tw = (const float*)d_in[4];
  float* out = (float*)d_out;

  f16* ws  = (f16*)d_ws;
  f16* xh  = ws + XH_OFF;
  f16* wh  = ws + WH_OFF;
  f16* sdt = ws + SD_OFF;
  float* biasp = (float*)(ws + BP_OFF);
  float* ptree = (float*)d_ws + PT_OFF_F;

  prep_all_k<<<7168, 256, 0, stream>>>(x, sw, ll, tw, sb, xh, wh, sdt, biasp);
  tree_gemm1<<<512, 512, 0, stream>>>(xh, wh, biasp, sdt, ptree);
  reduce_k<<<(NB * NCLS / 4) / 256, 256, 0, stream>>>(ptree, out);
}

// Round 7
// 199.132 us; speedup vs baseline: 1.1435x; 1.0338x over previous
//
#include <hip/hip_runtime.h>
#include <hip/hip_fp16.h>

typedef _Float16 f16;
typedef _Float16 f16x4 __attribute__((ext_vector_type(4)));
typedef _Float16 f16x8 __attribute__((ext_vector_type(8)));
typedef float    f32x4 __attribute__((ext_vector_type(4)));

constexpr int TREES = 16;
constexpr int NNODE = 255;
constexpr int NCLS  = 100;
constexpr int NCPAD = 112;
constexpr int NB    = 8192;
constexpr int DF    = 1024;
constexpr int KTOT  = TREES * 256;   // 4096

// workspace layout (half-element offsets)
constexpr size_t XH_OFF = 0;                                    // [8192][1024] f16
constexpr size_t WH_OFF = XH_OFF + (size_t)NB * DF;             // [16][256][1024] f16
constexpr size_t SD_OFF = WH_OFF + (size_t)TREES * 256 * DF;    // [112][4096] f16
constexpr size_t BP_OFF = SD_OFF + (size_t)NCPAD * KTOT;        // [16][256] f32 padded bias
constexpr size_t PT_OFF_F = (BP_OFF + 8192) / 2;                // [16][8192][100] f32 partials

#define WAIT_VMCNT(n) asm volatile("s_waitcnt vmcnt(" #n ")" ::: "memory")
__device__ __forceinline__ void BAR() {
  asm volatile("" ::: "memory");
  __builtin_amdgcn_s_barrier();
  asm volatile("" ::: "memory");
}

__device__ __forceinline__ void gload_lds16(const f16* g, f16* l) {
  __builtin_amdgcn_global_load_lds(
      (const __attribute__((address_space(1))) void*)g,
      (__attribute__((address_space(3))) void*)l, 16, 0, 0);
}

// ---------------- merged prep: x-cvt, w-cvt, leaf-softmax, bias-pad ----------------
__global__ void prep_all_k(const float* __restrict__ x, const float* __restrict__ w,
                           const float* __restrict__ ll, const float* __restrict__ twin,
                           const float* __restrict__ sb,
                           f16* __restrict__ xh, f16* __restrict__ wh,
                           f16* __restrict__ sdt, float* __restrict__ bp) {
  int bid = blockIdx.x;
  if (bid < 4096) {
    int i = bid * 256 + threadIdx.x;
    const float4* s = (const float4*)x + (size_t)i * 2;
    float4 u = s[0], v = s[1];
    f16x8 h = {(f16)u.x, (f16)u.y, (f16)u.z, (f16)u.w,
               (f16)v.x, (f16)v.y, (f16)v.z, (f16)v.w};
    *((f16x8*)xh + i) = h;
  } else if (bid < 6144) {
    int i = (bid - 4096) * 256 + threadIdx.x;
    int flat = i * 8;
    int t = flat >> 18;
    int r = (flat >> 10) & 255;
    int k = flat & 1023;
    f16x8 h;
    if (r < NNODE) {
      const float4* s = (const float4*)(w + ((size_t)(t * NNODE + r) * DF + k));
      float4 u = s[0], v = s[1];
      h = (f16x8){(f16)u.x, (f16)u.y, (f16)u.z, (f16)u.w,
                  (f16)v.x, (f16)v.y, (f16)v.z, (f16)v.w};
    } else {
      h = (f16x8){(f16)0.f, (f16)0.f, (f16)0.f, (f16)0.f,
                  (f16)0.f, (f16)0.f, (f16)0.f, (f16)0.f};
    }
    *((f16x8*)wh + i) = h;
  } else {
    int wv   = threadIdx.x >> 6;
    int lane = threadIdx.x & 63;
    int id   = (bid - 6144) * 4 + wv;    // 0..4095 = t*256 + node
    int t    = id >> 8;
    int node = id & 255;

    float wm = -1e30f;
#pragma unroll
    for (int i = 0; i < 16; ++i) wm = fmaxf(wm, twin[i]);
    float wsum = 0.f;
#pragma unroll
    for (int i = 0; i < 16; ++i) wsum += __expf(twin[i] - wm);
    float wt = __expf(twin[t] - wm) / wsum;

    const float* rowp = ll + (size_t)id * NCLS;
    float v1 = rowp[lane];
    bool has2 = (lane + 64) < NCLS;
    float v2 = has2 ? rowp[lane + 64] : -1e30f;
    float mx = fmaxf(v1, v2);
#pragma unroll
    for (int m = 32; m; m >>= 1) mx = fmaxf(mx, __shfl_xor(mx, m, 64));
    float e1 = __expf(v1 - mx);
    float e2 = has2 ? __expf(v2 - mx) : 0.f;
    float ss = e1 + e2;
#pragma unroll
    for (int m = 32; m; m >>= 1) ss += __shfl_xor(ss, m, 64);
    float inv = wt / ss;

    sdt[(size_t)lane * KTOT + id] = (f16)(e1 * inv);
    if (lane + 64 < NCPAD)
      sdt[(size_t)(lane + 64) * KTOT + id] = has2 ? (f16)(e2 * inv) : (f16)0.f;
    if (lane == 0) bp[id] = (node < NNODE) ? sb[(size_t)t * NNODE + node] : 0.f;
  }
}

// ---------------- fused 256x256 8-wave GEMM + sigmoid + mu + leaf-GEMM ----------------
// Faithful m201-style 4-phase/K-tile loop: BK=64 split into 2 k-halves.
// LDS main: dbuf 2 x 64KB, each { A[2][256][32], B[2][256][32] } k-half-major,
// half-tile = one (op, kh) = 16KB = contiguous DMA target (2 gloads/thread).
// Swizzle within a half: byte = (r*64 + k'*2) ^ ((r&7)<<4)  (bijective, 2-way banks).
// Phase p = (kh=p>>1, mhalf=p&1): stage 1 half-tile of kt+1; vmcnt(6) at p=0,2 only;
// BAR; ds_read 8/4 b128; setprio(1) 16 MFMA setprio(0); BAR.  Never vmcnt(0) in loop.
__global__ __launch_bounds__(512, 2) void tree_gemm1(
    const f16* __restrict__ xh, const f16* __restrict__ wh,
    const float* __restrict__ biasp, const f16* __restrict__ sdt,
    float* __restrict__ ptree) {
  __shared__ f16 smem[81920];  // 160 KiB (main loop uses first 128 KiB)
  char* smb = (char*)smem;

  const int tid  = threadIdx.x;
  const int lane = tid & 63;
  const int wid  = tid >> 6;
  const int l15  = lane & 15;
  const int lq   = lane >> 4;
  const int wrow = (wid >> 2) * 128;
  const int wcol = (wid & 3) * 64;

  // XCD rectangle decode: each XCD gets 8 trees x 8 row-blocks
  int bid  = blockIdx.x;
  int xcd  = bid & 7;
  int idx  = bid >> 3;
  int t    = (xcd & 1) * 8 + (idx & 7);
  int brow = (xcd >> 1) * 8 + (idx >> 3);

  const f16* xsrc = xh + (size_t)brow * 256 * DF;
  const f16* wsrc = wh + (size_t)t * 256 * DF;

  // stage half-tile (op, kh) of tile kt into buf cb. dst linear; src inverse-swizzled.
  // inverse of byte=(r*64+cs*16)^((r&7)<<4): r0=b6^b8, r1=b7, r2=b8, cs=b4^r0 | (b5^r1)<<1
  auto stage_ht = [&](int kt, int cb, int op, int kh) {
    const f16* srcb = (op == 0 ? xsrc : wsrc) + kt * 64 + kh * 32;
    f16* dstb = smem + cb * 32768 + op * 16384 + kh * 8192;   // half-elem offsets
#pragma unroll
    for (int ch = 0; ch < 2; ++ch) {
      int u  = ch * 512 + tid;                  // 16B unit, 0..1023
      int r0 = ((u >> 2) ^ (u >> 4)) & 1;
      int r1 = (u >> 3) & 1;
      int r2 = (u >> 4) & 1;
      int r  = r0 | (r1 << 1) | (r2 << 2) | ((u >> 5) << 3);
      int cs = ((u ^ r0) & 1) | ((((u >> 1) ^ r1) & 1) << 1);
      gload_lds16(srcb + (size_t)r * DF + cs * 8, dstb + u * 8);
    }
  };

  // sdt prefetch chunk c (rows 32c..32c+31) into S=[0,32K) — used as kt=15 ballast
  auto sdt_stage2 = [&](int c) {
#pragma unroll
    for (int ch = 0; ch < 2; ++ch) {
      int q  = c * 1024 + ch * 512 + tid;
      int rr = q >> 5;
      int jj = q & 31;
      gload_lds16(sdt + (size_t)rr * KTOT + t * 256 + ((jj * 8) ^ ((rr & 7) << 3)),
                  smem + q * 8);
    }
  };

  auto ldop = [&](const char* half_base, int row) -> f16x8 {
    return *(const f16x8*)(half_base + ((row * 64 + lq * 16) ^ ((row & 7) << 4)));
  };

  f32x4 acc[8][4];
#pragma unroll
  for (int m = 0; m < 8; ++m)
#pragma unroll
    for (int n = 0; n < 4; ++n) acc[m][n] = (f32x4){0.f, 0.f, 0.f, 0.f};

  // prologue: stage tile 0's 4 half-tiles into buf 0
  stage_ht(0, 0, 0, 0); stage_ht(0, 0, 1, 0);
  stage_ht(0, 0, 0, 1); stage_ht(0, 0, 1, 1);

  for (int kt = 0; kt < 16; ++kt) {
    const char* Acur = smb + (kt & 1) * 65536;          // A base (both k-halves)
    const char* Bcur = Acur + 32768;
    const int cn = (kt & 1) ^ 1;
    f16x8 af[4], bf[4];

    // ======== phase 0: kh0, m0-3 ========
    if (kt < 15) stage_ht(kt + 1, cn, 0, 0); else sdt_stage2(0);
    WAIT_VMCNT(6);            // drains (A,k0),(B,k0)@kt; 3 half-tiles stay in flight
    BAR();
#pragma unroll
    for (int m = 0; m < 4; ++m) af[m] = ldop(Acur, wrow + m * 16 + l15);
#pragma unroll
    for (int n = 0; n < 4; ++n) bf[n] = ldop(Bcur, wcol + n * 16 + l15);
    __builtin_amdgcn_s_setprio(1);
#pragma unroll
    for (int m = 0; m < 4; ++m)
#pragma unroll
      for (int n = 0; n < 4; ++n)
        acc[m][n] = __builtin_amdgcn_mfma_f32_16x16x32_f16(bf[n], af[m], acc[m][n], 0, 0, 0);
    __builtin_amdgcn_s_setprio(0);
    BAR();

    // ======== phase 1: kh0, m4-7 (bf reused; reads pre-BAR, data confirmed @p0) ====
#pragma unroll
    for (int m = 0; m < 4; ++m) af[m] = ldop(Acur, wrow + 64 + m * 16 + l15);
    if (kt < 15) stage_ht(kt + 1, cn, 1, 0);
    BAR();
    __builtin_amdgcn_sched_barrier(0);
    __builtin_amdgcn_s_setprio(1);
#pragma unroll
    for (int m = 0; m < 4; ++m)
#pragma unroll
      for (int n = 0; n < 4; ++n)
        acc[m + 4][n] = __builtin_amdgcn_mfma_f32_16x16x32_f16(bf[n], af[m], acc[m + 4][n], 0, 0, 0);
    __builtin_amdgcn_s_setprio(0);
    BAR();

    // ======== phase 2: kh1, m0-3 ========
    if (kt < 15) { stage_ht(kt + 1, cn, 0, 1); WAIT_VMCNT(6); }
    else         { sdt_stage2(1);              WAIT_VMCNT(4); }
    BAR();
#pragma unroll
    for (int m = 0; m < 4; ++m) af[m] = ldop(Acur + 16384, wrow + m * 16 + l15);
#pragma unroll
    for (int n = 0; n < 4; ++n) bf[n] = ldop(Bcur + 16384, wcol + n * 16 + l15);
    __builtin_amdgcn_s_setprio(1);
#pragma unroll
    for (int m = 0; m < 4; ++m)
#pragma unroll
      for (int n = 0; n < 4; ++n)
        acc[m][n] = __builtin_amdgcn_mfma_f32_16x16x32_f16(bf[n], af[m], acc[m][n], 0, 0, 0);
    __builtin_amdgcn_s_setprio(0);
    BAR();

    // ======== phase 3: kh1, m4-7 ========
#pragma unroll
    for (int m = 0; m < 4; ++m) af[m] = ldop(Acur + 16384, wrow + 64 + m * 16 + l15);
    if (kt < 15) stage_ht(kt + 1, cn, 1, 1);
    BAR();
    __builtin_amdgcn_sched_barrier(0);
    __builtin_amdgcn_s_setprio(1);
#pragma unroll
    for (int m = 0; m < 4; ++m)
#pragma unroll
      for (int n = 0; n < 4; ++n)
        acc[m + 4][n] = __builtin_amdgcn_mfma_f32_16x16x32_f16(bf[n], af[m], acc[m + 4][n], 0, 0, 0);
    __builtin_amdgcn_s_setprio(0);
    BAR();
  }

  // epilogue LDS regions: S=[0,32K) sdt (rows 0-63 already in flight),
  // U=[32K,96K) mu, P=[96K,160K) probs
  char* Sb = smb;
  char* Ub = smb + 32768;
  char* Pb = smb + 98304;

  auto stage_sdt = [&](int c0, int nrows) {
    int nch = nrows * 32;
    for (int q = tid; q < nch; q += 512) {
      int rr = q >> 5;
      int jj = q & 31;
      gload_lds16(sdt + (size_t)(c0 + rr) * KTOT + t * 256 + ((jj * 8) ^ ((rr & 7) << 3)),
                  smem + q * 8);
    }
  };

  // ---- sigmoid + bias, packed f16x4 (regs = 4 consecutive nodes per row) ----
  f16x4 ph[8][4];
#pragma unroll
  for (int m = 0; m < 8; ++m) {
#pragma unroll
    for (int n = 0; n < 4; ++n) {
      int col = wcol + n * 16 + lq * 4;
      float4 b4 = *(const float4*)(biasp + t * 256 + col);
#pragma unroll
      for (int reg = 0; reg < 4; ++reg) {
        float bv = (reg == 0) ? b4.x : (reg == 1) ? b4.y : (reg == 2) ? b4.z : b4.w;
        float z = acc[m][n][reg] + bv;
        ph[m][n][reg] = (f16)__builtin_amdgcn_rcpf(1.f + __expf(-z));
      }
    }
  }

  for (int h = 0; h < 2; ++h) {
    // P[128][256] f16, 16B-granularity swizzle: byte = (r*512 + node*2) ^ ((r&7)<<4)
    if ((wid >> 2) == h) {
#pragma unroll
      for (int m = 0; m < 8; ++m) {
#pragma unroll
        for (int n = 0; n < 4; ++n) {
          int r = m * 16 + l15;
          int nodeb = (wcol + n * 16 + lq * 4) * 2;
          *(f16x4*)(Pb + ((r * 512 + nodeb) ^ ((r & 7) << 4))) = ph[m][n];
        }
      }
    }
    __syncthreads();

    // ---- mu pass: 512 thr = 128 rows x 4 chunks; vectorized P reads ----
    {
      int r = tid >> 2;
      int c = tid & 3;
      auto PRs = [&](int node) -> float {
        return (float)*(const f16*)(Pb + ((r * 512 + node * 2) ^ ((r & 7) << 4)));
      };
      auto V8 = [&](int node) -> f16x8 {   // node must be multiple of 8
        return *(const f16x8*)(Pb + ((r * 512 + node * 2) ^ ((r & 7) << 4)));
      };
      float p0 = PRs(0);
      float p1 = PRs(1 + (c >> 1));
      float pr = ((c >> 1) ? p0 : 1.f - p0) * ((c & 1) ? p1 : 1.f - p1);
      float p2 = PRs(3 + c);
      float cur[64];
      {
        float mp = pr * p2;
        cur[1] = mp; cur[0] = pr - mp;
      }
      { // d=3: nodes 7+2c, 8+2c
        float q0 = PRs(7 + 2 * c), q1 = PRs(8 + 2 * c);
        float m1 = cur[1], mp1 = m1 * q1;
        cur[3] = mp1; cur[2] = m1 - mp1;
        float m0 = cur[0], mp0 = m0 * q0;
        cur[1] = mp0; cur[0] = m0 - mp0;
      }
      { // d=4: nodes 15+4c .. 18+4c
        float q[4];
        q[0] = PRs(15 + 4 * c);
        f16x4 v = *(const f16x4*)(Pb + ((r * 512 + (16 + 4 * c) * 2) ^ ((r & 7) << 4)));
        q[1] = (float)v[0]; q[2] = (float)v[1]; q[3] = (float)v[2];
#pragma unroll
        for (int i = 3; i >= 0; --i) {
          float mv = cur[i], mp = mv * q[i];
          cur[2 * i + 1] = mp; cur[2 * i] = mv - mp;
        }
      }
      { // d=5: nodes 31+8c .. 38+8c
        float q[8];
        q[0] = PRs(31 + 8 * c);
        f16x8 v = V8(32 + 8 * c);
#pragma unroll
        for (int j = 0; j < 7; ++j) q[j + 1] = (float)v[j];
#pragma unroll
        for (int i = 7; i >= 0; --i) {
          float mv = cur[i], mp = mv * q[i];
          cur[2 * i + 1] = mp; cur[2 * i] = mv - mp;
        }
      }
      { // d=6: nodes 63+16c .. 78+16c
        float q[16];
        q[0] = PRs(63 + 16 * c);
        f16x8 v0 = V8(64 + 16 * c), v1 = V8(72 + 16 * c);
#pragma unroll
        for (int j = 0; j < 8; ++j) q[j + 1] = (float)v0[j];
#pragma unroll
        for (int j = 0; j < 7; ++j) q[j + 9] = (float)v1[j];
#pragma unroll
        for (int i = 15; i >= 0; --i) {
          float mv = cur[i], mp = mv * q[i];
          cur[2 * i + 1] = mp; cur[2 * i] = mv - mp;
        }
      }
      { // d=7: nodes 127+32c .. 158+32c
        float q[32];
        q[0] = PRs(127 + 32 * c);
        f16x8 v0 = V8(128 + 32 * c), v1 = V8(136 + 32 * c);
        f16x8 v2 = V8(144 + 32 * c), v3 = V8(152 + 32 * c);
#pragma unroll
        for (int j = 0; j < 8; ++j) q[j + 1]  = (float)v0[j];
#pragma unroll
        for (int j = 0; j < 8; ++j) q[j + 9]  = (float)v1[j];
#pragma unroll
        for (int j = 0; j < 8; ++j) q[j + 17] = (float)v2[j];
#pragma unroll
        for (int j = 0; j < 7; ++j) q[j + 25] = (float)v3[j];
#pragma unroll
        for (int i = 31; i >= 0; --i) {
          float mv = cur[i], mp = mv * q[i];
          cur[2 * i + 1] = mp; cur[2 * i] = mv - mp;
        }
      }
      // write mu -> U [128][256] f16, swizzle (r&7)<<4
#pragma unroll
      for (int g = 0; g < 8; ++g) {
        f16x8 v;
#pragma unroll
        for (int jj = 0; jj < 8; ++jj) v[jj] = (f16)cur[g * 8 + jj];
        *(f16x8*)(Ub + ((r * 512 + c * 128 + g * 16) ^ ((r & 7) << 4))) = v;
      }
    }
    WAIT_VMCNT(0);      // S chunk arrived (own wave's loads)
    __syncthreads();    // all waves: S landed + U visible

    // ---- leaf-GEMM: out(128x112) = mu(128x256) @ sdt_t(112x256) ----
    f32x4 acc2[7];
#pragma unroll
    for (int n = 0; n < 7; ++n) acc2[n] = (f32x4){0.f, 0.f, 0.f, 0.f};
    int arow = wid * 16 + l15;

#pragma unroll
    for (int n = 0; n < 4; ++n) {
#pragma unroll
      for (int s = 0; s < 8; ++s) {
        f16x8 a = *(const f16x8*)(Ub + ((arow * 512 + s * 64 + lq * 16) ^ ((arow & 7) << 4)));
        int br = n * 16 + l15;
        f16x8 b = *(const f16x8*)(Sb + ((br * 512 + s * 64 + lq * 16) ^ ((br & 7) << 4)));
        acc2[n] = __builtin_amdgcn_mfma_f32_16x16x32_f16(a, b, acc2[n], 0, 0, 0);
      }
    }
    __syncthreads();          // S rows 0..63 reads done
    stage_sdt(64, 48);        // S rows 64..111 (rebased at S[0])
    WAIT_VMCNT(0);
    __syncthreads();
#pragma unroll
    for (int n = 4; n < 7; ++n) {
#pragma unroll
      for (int s = 0; s < 8; ++s) {
        f16x8 a = *(const f16x8*)(Ub + ((arow * 512 + s * 64 + lq * 16) ^ ((arow & 7) << 4)));
        int br = (n - 4) * 16 + l15;
        f16x8 b = *(const f16x8*)(Sb + ((br * 512 + s * 64 + lq * 16) ^ ((br & 7) << 4)));
        acc2[n] = __builtin_amdgcn_mfma_f32_16x16x32_f16(a, b, acc2[n], 0, 0, 0);
      }
    }

    float* pt = ptree + ((size_t)t * NB + brow * 256 + h * 128) * NCLS;
#pragma unroll
    for (int n = 0; n < 7; ++n) {
      int col = n * 16 + l15;
      if (col < NCLS) {
#pragma unroll
        for (int reg = 0; reg < 4; ++reg) {
          int r = wid * 16 + lq * 4 + reg;
          pt[(size_t)r * NCLS + col] = acc2[n][reg];
        }
      }
    }
    if (h == 0) {
      __syncthreads();        // S reads + P reads of half 0 complete everywhere
      stage_sdt(0, 64);       // re-issue S rows 0..63 for half 1
    }
  }
}

// ---------------- reduce over trees ----------------
__global__ void reduce_k(const float* __restrict__ pt, float* __restrict__ out) {
  int i = blockIdx.x * 256 + threadIdx.x;
  constexpr size_t STRIDE4 = (size_t)NB * NCLS / 4;
  const float4* p = (const float4*)pt + i;
  float4 s = p[0];
#pragma unroll
  for (int t = 1; t < TREES; ++t) {
    float4 v = p[t * STRIDE4];
    s.x += v.x; s.y += v.y; s.z += v.z; s.w += v.w;
  }
  ((float4*)out)[i] = s;
}

// ---------------- launch ----------------
extern "C" void kernel_launch(void* const* d_in, const int* in_sizes, int n_in,
                              void* d_out, int out_size, void* d_ws, size_t ws_size,
                              hipStream_t stream) {
  const float* x  = (const float*)d_in[0];
  const float* sw = (const float*)d_in[1];
  const float* sb = (const float*)d_in[2];
  const float* ll = (const float*)d_in[3];
  const float* tw = (const float*)d_in[4];
  float* out = (float*)d_out;

  f16* ws  = (f16*)d_ws;
  f16* xh  = ws + XH_OFF;
  f16* wh  = ws + WH_OFF;
  f16* sdt = ws + SD_OFF;
  float* biasp = (float*)(ws + BP_OFF);
  float* ptree = (float*)d_ws + PT_OFF_F;

  prep_all_k<<<7168, 256, 0, stream>>>(x, sw, ll, tw, sb, xh, wh, sdt, biasp);
  tree_gemm1<<<512, 512, 0, stream>>>(xh, wh, biasp, sdt, ptree);
  reduce_k<<<(NB * NCLS / 4) / 256, 256, 0, stream>>>(ptree, out);
}